// Round 1
// 767.553 us; speedup vs baseline: 1.0167x; 1.0167x over previous
//
#include <hip/hip_runtime.h>
#include <hip/hip_bf16.h>
#include <cmath>
#include <cstdint>

// Problem constants (from reference): N=100000, D=512, H1=16, C=40, NNZ=3.2M
#define DD 512
#define HH 16
#define CC 40
#define KC 32   // K-chunk for k_gemm1 LDS staging

// ---------------------------------------------------------------------------
// K1: X1 = H @ W1   (N x 512) @ (512 x 16) -> (N x 16)
// 128 threads / 128 rows per block -> grid=782 (all 256 CUs busy).
// H staged through LDS in coalesced 128B segments (8 lanes x float4 per row),
// pitch 33 so compute-phase reads are 2-way bank aliased (free per m136).
// W1 read with lane-invariant addresses -> compiler emits scalar s_loads
// (K$-resident, no LDS/VMEM pressure).
// ---------------------------------------------------------------------------
__global__ __launch_bounds__(128) void k_gemm1(const float* __restrict__ Hm,
                                               const float* __restrict__ W1,
                                               float* __restrict__ X1,
                                               int nrows) {
    __shared__ float hs[128 * (KC + 1)];
    const int row = blockIdx.x * 128 + (int)threadIdx.x;

    float acc[HH];
#pragma unroll
    for (int j = 0; j < HH; ++j) acc[j] = 0.f;

    for (int kc = 0; kc < DD; kc += KC) {
        __syncthreads();  // protect hs reuse from previous chunk's compute
        // stage 128 rows x KC floats, coalesced: 8 consecutive lanes cover one
        // row's 128B chunk.
#pragma unroll
        for (int it = 0; it < (128 * KC / 4) / 128; ++it) {
            int f  = it * 128 + (int)threadIdx.x;
            int r  = f >> 3;       // KC/4 = 8 float4 per row
            int c4 = f & 7;
            int gr = blockIdx.x * 128 + r;
            float4 v = make_float4(0.f, 0.f, 0.f, 0.f);
            if (gr < nrows)
                v = *reinterpret_cast<const float4*>(&Hm[(size_t)gr * DD + kc + c4 * 4]);
            float* dst = &hs[r * (KC + 1) + c4 * 4];  // pitch 33: scalar stores (unaligned for b128)
            dst[0] = v.x; dst[1] = v.y; dst[2] = v.z; dst[3] = v.w;
        }
        __syncthreads();

        const float* hrow = &hs[threadIdx.x * (KC + 1)];
#pragma unroll
        for (int kk = 0; kk < KC; ++kk) {
            float h = hrow[kk];  // bank (t+kk)%32 across wave: 2-way alias, free
            const float4* wr = reinterpret_cast<const float4*>(&W1[(kc + kk) * HH]);
            float4 w0 = wr[0], w1v = wr[1], w2v = wr[2], w3v = wr[3];
            acc[0]  += h * w0.x;  acc[1]  += h * w0.y;  acc[2]  += h * w0.z;  acc[3]  += h * w0.w;
            acc[4]  += h * w1v.x; acc[5]  += h * w1v.y; acc[6]  += h * w1v.z; acc[7]  += h * w1v.w;
            acc[8]  += h * w2v.x; acc[9]  += h * w2v.y; acc[10] += h * w2v.z; acc[11] += h * w2v.w;
            acc[12] += h * w3v.x; acc[13] += h * w3v.y; acc[14] += h * w3v.z; acc[15] += h * w3v.w;
        }
    }

    if (row < nrows) {
        float4* outp = reinterpret_cast<float4*>(&X1[(size_t)row * HH]);
#pragma unroll
        for (int j4 = 0; j4 < 4; ++j4)
            outp[j4] = make_float4(acc[j4 * 4 + 0], acc[j4 * 4 + 1],
                                   acc[j4 * 4 + 2], acc[j4 * 4 + 3]);
    }
}

// ---------------------------------------------------------------------------
// CSR build: histogram -> 3-kernel exclusive scan -> fill (packed col/val).
// Same graph serves both SpMM layers, so this is amortized 2x.
// ---------------------------------------------------------------------------
__global__ __launch_bounds__(256) void k_hist(const int* __restrict__ rows,
                                              int* __restrict__ cnt, int nnz) {
    int e = blockIdx.x * 256 + (int)threadIdx.x;
    if (e < nnz) atomicAdd(&cnt[rows[e]], 1);
}

__global__ __launch_bounds__(256) void k_scan1(const int* __restrict__ cnt,
                                               int* __restrict__ rp,
                                               int* __restrict__ bsum, int n) {
    __shared__ int sd[256];
    int t = (int)threadIdx.x;
    int i = blockIdx.x * 256 + t;
    int v = (i < n) ? cnt[i] : 0;
    sd[t] = v;
    __syncthreads();
    for (int off = 1; off < 256; off <<= 1) {
        int x = (t >= off) ? sd[t - off] : 0;
        __syncthreads();
        sd[t] += x;
        __syncthreads();
    }
    if (i < n) rp[i] = sd[t] - v;                 // exclusive within block
    if (t == 255) bsum[blockIdx.x] = sd[255];     // block total
}

__global__ __launch_bounds__(512) void k_scan2(int* __restrict__ bsum, int nb) {
    __shared__ int sd[512];
    int t = (int)threadIdx.x;
    int v = (t < nb) ? bsum[t] : 0;
    sd[t] = v;
    __syncthreads();
    for (int off = 1; off < 512; off <<= 1) {
        int x = (t >= off) ? sd[t - off] : 0;
        __syncthreads();
        sd[t] += x;
        __syncthreads();
    }
    if (t < nb) bsum[t] = sd[t] - v;              // exclusive across blocks
}

__global__ __launch_bounds__(256) void k_scan3(int* __restrict__ rp,
                                               const int* __restrict__ bsum,
                                               int n, int nnz) {
    int i = blockIdx.x * 256 + (int)threadIdx.x;
    if (i < n) rp[i] += bsum[blockIdx.x];
    if (i == 0) rp[n] = nnz;
}

__global__ __launch_bounds__(256) void k_fill(const int* __restrict__ rows,
                                              const int* __restrict__ cols,
                                              const float* __restrict__ vals,
                                              const int* __restrict__ rp,
                                              int* __restrict__ fill,
                                              int2* __restrict__ pairs, int nnz) {
    int e = blockIdx.x * 256 + (int)threadIdx.x;
    if (e >= nnz) return;
    int r = rows[e];
    int slot = rp[r] + atomicAdd(&fill[r], 1);    // order within row arbitrary (fp-assoc ok)
    pairs[slot] = make_int2(cols[e], __float_as_int(vals[e]));
}

// ---------------------------------------------------------------------------
// Gather SpMM: S[row] = sum_e val_e * f(X[col_e]),  f = identity (layer 1)
// or relu(x + b1) (layer 2 fused). 4 lanes per row, each owns a float4 of the
// 16 features: one coalesced 64B gather per edge, zero atomics, single write.
// ---------------------------------------------------------------------------
template <int RELU_IN>
__global__ __launch_bounds__(256) void k_spmm_csr(const int* __restrict__ rp,
                                                  const int2* __restrict__ pairs,
                                                  const float* __restrict__ X,
                                                  float* __restrict__ S,
                                                  const float* __restrict__ bias,
                                                  int nrows) {
    int gid = blockIdx.x * 256 + (int)threadIdx.x;
    int row = gid >> 2;
    int j4  = (gid & 3) * 4;
    if (row >= nrows) return;

    int s = rp[row], e = rp[row + 1];
    float4 b = make_float4(0.f, 0.f, 0.f, 0.f);
    if (RELU_IN) b = *reinterpret_cast<const float4*>(&bias[j4]);

    float a0 = 0.f, a1 = 0.f, a2 = 0.f, a3 = 0.f;
    for (int k = s; k < e; ++k) {
        int2 p  = pairs[k];                        // broadcast within 4-lane group
        float v = __int_as_float(p.y);
        float4 x = *reinterpret_cast<const float4*>(&X[(size_t)p.x * HH + j4]);
        if (RELU_IN) {
            x.x = fmaxf(x.x + b.x, 0.f); x.y = fmaxf(x.y + b.y, 0.f);
            x.z = fmaxf(x.z + b.z, 0.f); x.w = fmaxf(x.w + b.w, 0.f);
        }
        a0 += v * x.x; a1 += v * x.y; a2 += v * x.z; a3 += v * x.w;
    }
    *reinterpret_cast<float4*>(&S[(size_t)row * HH + j4]) = make_float4(a0, a1, a2, a3);
}

// ---------------------------------------------------------------------------
// Fallback scatter spmm (used only if workspace too small for CSR).
// ---------------------------------------------------------------------------
__global__ __launch_bounds__(256) void k_spmm(const int* __restrict__ rows,
                                              const int* __restrict__ cols,
                                              const float* __restrict__ vals,
                                              const float* __restrict__ X,
                                              float* __restrict__ S,
                                              const float* __restrict__ bias,
                                              int relu_in, int nnz) {
    long long idx = (long long)blockIdx.x * 256 + threadIdx.x;
    if (idx >= (long long)nnz * HH) return;
    int e = (int)(idx >> 4);
    int j = (int)(idx & 15);
    int c = cols[e];
    int r = rows[e];
    float v = vals[e];
    float x = X[(size_t)c * HH + j];
    if (relu_in) {
        x = x + bias[j];
        x = x > 0.f ? x : 0.f;
    }
    atomicAdd(&S[(size_t)r * HH + j], v * x);
}

// ---------------------------------------------------------------------------
// K4: out = log_softmax(relu(T @ W2 + b2)).  One thread per row.
// ---------------------------------------------------------------------------
__global__ __launch_bounds__(256) void k_out(const float* __restrict__ T,
                                             const float* __restrict__ W2,
                                             const float* __restrict__ b2,
                                             float* __restrict__ out,
                                             int nrows) {
    __shared__ float w2s[HH * CC];
    __shared__ float b2s[CC];
    for (int i = (int)threadIdx.x; i < HH * CC; i += 256) w2s[i] = W2[i];
    if (threadIdx.x < CC) b2s[threadIdx.x] = b2[threadIdx.x];
    __syncthreads();

    int row = blockIdx.x * 256 + (int)threadIdx.x;
    if (row >= nrows) return;

    float t[HH];
#pragma unroll
    for (int k4 = 0; k4 < HH; k4 += 4) {
        float4 tv = *reinterpret_cast<const float4*>(&T[(size_t)row * HH + k4]);
        t[k4] = tv.x; t[k4 + 1] = tv.y; t[k4 + 2] = tv.z; t[k4 + 3] = tv.w;
    }

    float y[CC];
#pragma unroll
    for (int j = 0; j < CC; ++j) {
        float a = b2s[j];
#pragma unroll
        for (int k = 0; k < HH; ++k) a += t[k] * w2s[k * CC + j];
        y[j] = a > 0.f ? a : 0.f;
    }

    float m = y[0];
#pragma unroll
    for (int j = 1; j < CC; ++j) m = fmaxf(m, y[j]);
    float s = 0.f;
#pragma unroll
    for (int j = 0; j < CC; ++j) s += __expf(y[j] - m);
    float ls = __logf(s) + m;

    float4* op = reinterpret_cast<float4*>(&out[(size_t)row * CC]);
#pragma unroll
    for (int j4 = 0; j4 < CC / 4; ++j4)
        op[j4] = make_float4(y[j4 * 4 + 0] - ls, y[j4 * 4 + 1] - ls,
                             y[j4 * 4 + 2] - ls, y[j4 * 4 + 3] - ls);
}

// ---------------------------------------------------------------------------
// Inputs (setup_inputs order):
//  0: H      (N*512 f32)     1: A_vals (NNZ f32)   2: W1 (512*16 f32)
//  3: b1     (16 f32)        4: W2     (16*40 f32) 5: b2 (40 f32)
//  6: A_rows (NNZ i32)       7: A_cols (NNZ i32)
// Output: N*40 f32 (log_softmax)
// ---------------------------------------------------------------------------
extern "C" void kernel_launch(void* const* d_in, const int* in_sizes, int n_in,
                              void* d_out, int out_size, void* d_ws, size_t ws_size,
                              hipStream_t stream) {
    const float* Hm  = (const float*)d_in[0];
    const float* Av  = (const float*)d_in[1];
    const float* W1  = (const float*)d_in[2];
    const float* b1  = (const float*)d_in[3];
    const float* W2  = (const float*)d_in[4];
    const float* b2  = (const float*)d_in[5];
    const int*   Ar  = (const int*)d_in[6];
    const int*   Ac  = (const int*)d_in[7];
    float*       out = (float*)d_out;

    const int N   = in_sizes[0] / DD;
    const int NNZ = in_sizes[6];

    // Workspace layout
    float* X1  = (float*)d_ws;                 // N*16
    float* S1  = X1 + (size_t)N * HH;          // N*16
    float* T   = S1 + (size_t)N * HH;          // N*16
    int*   rp  = (int*)(T + (size_t)N * HH);   // N+2 (row_ptr, padded)
    int*   cnt = rp + (N + 2);                 // N
    int*   fil = cnt + N;                      // N (contiguous with cnt for one memset)
    int*   bsum = fil + N;                     // 1024 block sums
    int2*  pairs = (int2*)((((uintptr_t)(bsum + 1024)) + 7) & ~(uintptr_t)7);  // NNZ (col,val)

    const int NB = (N + 255) / 256;
    size_t need = ((size_t)(pairs + NNZ) - (size_t)d_ws) - (size_t)0;
    bool csr_ok = (ws_size >= (size_t)((char*)(pairs + NNZ) - (char*)d_ws)) && (NB <= 512);
    (void)need;

    // K1: X1 = H @ W1 (independent of CSR build)
    int g1 = (N + 127) / 128;
    k_gemm1<<<g1, 128, 0, stream>>>(Hm, W1, X1, N);

    if (csr_ok) {
        // CSR build (once, reused by both layers)
        hipMemsetAsync(cnt, 0, (size_t)2 * N * sizeof(int), stream);  // cnt + fil
        int ge = (NNZ + 255) / 256;
        k_hist <<<ge, 256, 0, stream>>>(Ar, cnt, NNZ);
        k_scan1<<<NB, 256, 0, stream>>>(cnt, rp, bsum, N);
        k_scan2<<<1, 512, 0, stream>>>(bsum, NB);
        k_scan3<<<NB, 256, 0, stream>>>(rp, bsum, N, NNZ);
        k_fill <<<ge, 256, 0, stream>>>(Ar, Ac, Av, rp, fil, pairs, NNZ);

        // Gather SpMM x2 (no atomics)
        int gs = (N * 4 + 255) / 256;
        k_spmm_csr<0><<<gs, 256, 0, stream>>>(rp, pairs, X1, S1, b1, N);
        k_spmm_csr<1><<<gs, 256, 0, stream>>>(rp, pairs, S1, T,  b1, N);
    } else {
        // Fallback: scatter atomics (previous behavior)
        hipMemsetAsync(S1, 0, (size_t)2 * N * HH * sizeof(float), stream);
        long long work = (long long)NNZ * HH;
        int g2 = (int)((work + 255) / 256);
        k_spmm<<<g2, 256, 0, stream>>>(Ar, Ac, Av, X1, S1, b1, 0, NNZ);
        k_spmm<<<g2, 256, 0, stream>>>(Ar, Ac, Av, S1, T,  b1, 1, NNZ);
    }

    // K4: out = log_softmax(relu(T @ W2 + b2))
    int g4 = (N + 255) / 256;
    k_out<<<g4, 256, 0, stream>>>(T, W2, b2, out, N);
}